// Round 4
// baseline (1015.376 us; speedup 1.0000x reference)
//
#include <hip/hip_runtime.h>

#define MB 4
#define CC 3
#define MM 192
#define NN 192
#define PP 32
#define KITER 8
#define MN (MM*NN)          /* 36864  */
#define CMN (CC*MN)         /* 110592 */
#define IMG (MB*CMN)        /* 442368 */
#define ASZ (MB*PP*CMN)     /* 14155776 */

#define PSPLIT 8
#define PCHUNK (PP/PSPLIT)  /* 4 */

#define S3 0.57735026918962576f
#define S2 0.70710678118654752f
#define S6 0.40824829046386302f
#define W_CH 0.8f
#define EPSV 1e-8f
#define RADIUS 6.6510751010644885f   /* 0.02*sqrt(3*192*192) */

#define TD 64        /* output tile dim */
#define HALO 3
#define HT2 70       /* TD + 6 */
#define HS2 76       /* LDS row stride: 304B (16B-aligned), 4-row offset = 16 banks */
#define STG (HT2*HT2)   /* 4900 */
#define NSTG 20         /* ceil(4900/256) */

__device__ __forceinline__ float softf(float x, float t) {
    float m = fabsf(x) - t;
    return m > 0.f ? copysignf(m, x) : 0.f;
}

// partial conv: part[s] = sum_{p in chunk s} xcorr(a[b,p,c], B[p,c])
// 4x4 outputs per thread on a 64x64 tile.
__global__ __launch_bounds__(256) void k_conv_part(
    const float* __restrict__ a, const float* __restrict__ Bw,
    float* __restrict__ part)
{
    const int bc = blockIdx.z % (MB*CC);
    const int s  = blockIdx.z / (MB*CC);
    const int b = bc / CC, c = bc % CC;
    const int m0 = blockIdx.y * TD, n0 = blockIdx.x * TD;
    __shared__ float sT[HT2 * HS2];
    const int tc = threadIdx.x & 15;   // col group: cols tc*4..+3
    const int tr = threadIdx.x >> 4;   // row group: rows tr*4..+3
    const int p0 = s * PCHUNK;

    int sidx[NSTG];
    #pragma unroll
    for (int j = 0; j < NSTG; ++j) {
        const int i = threadIdx.x + j*256;
        if (i < STG) {
            const int sr = i / HT2, scn = i - sr*HT2;
            const int gm = m0 + sr - HALO, gn = n0 + scn - HALO;
            sidx[j] = ((unsigned)gm < MM && (unsigned)gn < NN) ? (gm*NN + gn) : -1;
        } else sidx[j] = -2;
    }
    float pf[NSTG];
    {
        const float* ap = a + (size_t)((b*PP + p0)*CC + c) * MN;
        #pragma unroll
        for (int j = 0; j < NSTG; ++j)
            if (sidx[j] != -2) pf[j] = (sidx[j] >= 0) ? ap[sidx[j]] : 0.f;
    }
    float acc[4][4];
    #pragma unroll
    for (int r = 0; r < 4; ++r)
        #pragma unroll
        for (int j = 0; j < 4; ++j) acc[r][j] = 0.f;

    #pragma unroll 1
    for (int pp = 0; pp < PCHUNK; ++pp) {
        __syncthreads();   // prior compute done, safe to overwrite LDS
        #pragma unroll
        for (int j = 0; j < NSTG; ++j) {
            const int i = threadIdx.x + j*256;
            if (i < STG) { const int sr = i / HT2; sT[i + 6*sr] = pf[j]; }
        }
        __syncthreads();
        if (pp + 1 < PCHUNK) {   // issue next plane's loads; hide under compute
            const float* ap = a + (size_t)((b*PP + p0 + pp + 1)*CC + c) * MN;
            #pragma unroll
            for (int j = 0; j < NSTG; ++j)
                if (sidx[j] != -2) pf[j] = (sidx[j] >= 0) ? ap[sidx[j]] : 0.f;
        }
        const float* bp = Bw + ((p0 + pp)*CC + c) * 49;
        #pragma unroll
        for (int ir = 0; ir < 10; ++ir) {
            const int base = (tr*4 + ir)*HS2 + tc*4;
            const float4 q0 = *(const float4*)&sT[base];
            const float4 q1 = *(const float4*)&sT[base + 4];
            const float2 q2 = *(const float2*)&sT[base + 8];
            const float w[10] = {q0.x,q0.y,q0.z,q0.w,q1.x,q1.y,q1.z,q1.w,q2.x,q2.y};
            #pragma unroll
            for (int r = 0; r < 4; ++r) {
                const int du = ir - r;
                if (du >= 0 && du <= 6) {
                    #pragma unroll
                    for (int v = 0; v < 7; ++v) {
                        const float bv = bp[du*7 + v];
                        #pragma unroll
                        for (int j = 0; j < 4; ++j) acc[r][j] += w[v+j] * bv;
                    }
                }
            }
        }
    }
    #pragma unroll
    for (int r = 0; r < 4; ++r) {
        const int idx = (b*CC + c)*MN + (m0 + tr*4 + r)*NN + n0 + tc*4;
        float4 o; o.x = acc[r][0]; o.y = acc[r][1]; o.z = acc[r][2]; o.w = acc[r][3];
        *(float4*)&part[(size_t)s*IMG + idx] = o;
    }
}

// a_out = soft(a_in + g2 * convT_csc(r, B), g2*lam1)  for p in chunk s
__global__ __launch_bounds__(256) void k_a_update(
    const float* __restrict__ a_in, const float* __restrict__ rr,
    const float* __restrict__ Bw, float* __restrict__ a_out,
    const float* __restrict__ gam2, const float* __restrict__ lam1, int k)
{
    const int bc = blockIdx.z % (MB*CC);
    const int s  = blockIdx.z / (MB*CC);
    const int b = bc / CC, c = bc % CC;
    const int m0 = blockIdx.y * TD, n0 = blockIdx.x * TD;
    const float g2  = gam2[k];
    const float thr = g2 * lam1[k];
    __shared__ float sT[HT2 * HS2];
    const float* rp = rr + (b*CC + c)*MN;
    for (int i = threadIdx.x; i < STG; i += 256) {
        const int sr = i / HT2, scn = i - sr*HT2;
        const int gm = m0 + sr - HALO, gn = n0 + scn - HALO;
        float v = 0.f;
        if ((unsigned)gm < MM && (unsigned)gn < NN) v = rp[gm*NN + gn];
        sT[sr*HS2 + scn] = v;
    }
    __syncthreads();
    const int tc = threadIdx.x & 15;
    const int tr = threadIdx.x >> 4;
    const int p0 = s * PCHUNK;
    #pragma unroll 1
    for (int pp = 0; pp < PCHUNK; ++pp) {
        const int p = p0 + pp;
        const float* bp = Bw + (p*CC + c) * 49;
        float acc[4][4];
        #pragma unroll
        for (int r = 0; r < 4; ++r)
            #pragma unroll
            for (int j = 0; j < 4; ++j) acc[r][j] = 0.f;
        #pragma unroll
        for (int ir = 0; ir < 10; ++ir) {
            const int base = (tr*4 + ir)*HS2 + tc*4;
            const float4 q0 = *(const float4*)&sT[base];
            const float4 q1 = *(const float4*)&sT[base + 4];
            const float2 q2 = *(const float2*)&sT[base + 8];
            const float w[10] = {q0.x,q0.y,q0.z,q0.w,q1.x,q1.y,q1.z,q1.w,q2.x,q2.y};
            #pragma unroll
            for (int r = 0; r < 4; ++r) {
                const int du = ir - r;            // u = 6-du, flipped kernel
                if (du >= 0 && du <= 6) {
                    #pragma unroll
                    for (int v = 0; v < 7; ++v) {
                        const float bv = bp[(6-du)*7 + (6-v)];
                        #pragma unroll
                        for (int j = 0; j < 4; ++j) acc[r][j] += w[v+j] * bv;
                    }
                }
            }
        }
        #pragma unroll
        for (int r = 0; r < 4; ++r) {
            const size_t idx = (size_t)((b*PP + p)*CC + c)*MN + (m0 + tr*4 + r)*NN + n0 + tc*4;
            const float4 av = *(const float4*)&a_in[idx];
            float4 o;
            o.x = softf(av.x + g2*acc[r][0], thr);
            o.y = softf(av.y + g2*acc[r][1], thr);
            o.z = softf(av.z + g2*acc[r][2], thr);
            o.w = softf(av.w + g2*acc[r][3], thr);
            *(float4*)&a_out[idx] = o;
        }
    }
}

// Fused: lazy y2 projection (iter k-1) + fold conv partials + x update +
//        y2 accumulation + per-batch norm reduction (one atomic/block).
// sums layout: sums[k*64 + b*16]
__global__ __launch_bounds__(256) void k_x_update(
    const float* __restrict__ xbef, const float* __restrict__ part,
    float* __restrict__ rb,
    const float* __restrict__ y1, float* __restrict__ y2,
    const float* __restrict__ mask, const float* __restrict__ z,
    const float* __restrict__ gam1, const float* __restrict__ gam3, int k,
    float* __restrict__ xaft, float* __restrict__ sums)
{
    const int i = blockIdx.x*256 + threadIdx.x;   // grid exactly covers MB*MN
    const int b = i / MN, mn = i - b*MN;
    const int m = mn / NN, n = mn - m*NN;
    const float g1 = gam1[k];
    const float g3 = gam3[k];
    const float inv3 = 1.f / (g3 + EPSV);
    float g3p = 0.f, invp = 0.f, scale_prev = 0.f;
    if (k > 0) {
        g3p  = gam3[k-1];
        invp = 1.f / (g3p + EPSV);
        const float nrm = sqrtf(sums[(k-1)*64 + b*16]);
        scale_prev = fminf(1.f, RADIUS / fmaxf(nrm, 1e-12f));
    }
    float dt[3];
    #pragma unroll
    for (int e = 0; e < 3; ++e) {
        const float* yv = y1 + ((size_t)(b*2 + 0)*CC + e)*MN;
        const float* yh = y1 + ((size_t)(b*2 + 1)*CC + e)*MN;
        float dv = (m > 0 ? yv[mn - NN] : 0.f) - (m < MM-1 ? yv[mn] : 0.f);
        float dh = (n > 0 ? yh[mn - 1]  : 0.f) - (n < NN-1 ? yh[mn] : 0.f);
        dt[e] = dv + dh;
    }
    const float ct0 = S3*dt[0] + S2*dt[1] + S6*dt[2];
    const float ct1 = S3*dt[0] - S2*dt[1] + S6*dt[2];
    const float ct2 = S3*dt[0]            - 2.f*S6*dt[2];
    const float ct[3] = {ct0, ct1, ct2};
    const bool last = (k == KITER-1);
    float dsq = 0.f;
    #pragma unroll
    for (int c = 0; c < 3; ++c) {
        const int idx = (b*CC + c)*MN + mn;
        float conv = 0.f;
        #pragma unroll
        for (int ss = 0; ss < PSPLIT; ++ss) conv += part[(size_t)ss*IMG + idx];
        const float xb = xbef[idx];
        const float r = xb - conv;
        const float zi = z[idx];
        const float mk = mask[idx];
        float y2b = 0.f;
        if (k > 0) {   // lazily apply iter-(k-1) L2-ball projection
            const float yr = y2[idx];
            const float d = yr*invp - zi;
            y2b = yr - g3p*(zi + d*scale_prev);
        }
        float x = xb - g1*(r + ct[c] + mk*y2b);
        x = fminf(fmaxf(x, 0.f), 1.f);
        xaft[idx] = x;
        if (!last) {
            rb[idx] = r;
            const float v  = 2.f*x - xb;
            const float yn = y2b + g3*(mk*v);
            y2[idx] = yn;               // post-acc, pre-proj (proj applied lazily)
            const float d2 = yn*inv3 - zi;
            dsq += d2*d2;
        }
    }
    if (!last) {
        #pragma unroll
        for (int off = 32; off > 0; off >>= 1) dsq += __shfl_down(dsq, off, 64);
        __shared__ float red[4];
        if ((threadIdx.x & 63) == 0) red[threadIdx.x >> 6] = dsq;
        __syncthreads();
        if (threadIdx.x == 0)
            atomicAdd(&sums[k*64 + b*16], red[0] + red[1] + red[2] + red[3]);
    }
}

// y1 += g3*Dop(Cop(v)); y1 -= g3*prox_dvtv(y1/(g3+eps), lam2/(g3+eps), w)
__global__ __launch_bounds__(256) void k_y1_update(
    float* __restrict__ y1, const float* __restrict__ xaft,
    const float* __restrict__ xbef,
    const float* __restrict__ gam3, const float* __restrict__ lam2, int k)
{
    const int i = blockIdx.x*256 + threadIdx.x;
    if (i >= MB*MN) return;
    const int b = i / MN, mn = i - b*MN;
    const int m = mn / NN, n = mn - m*NN;
    const float g3  = gam3[k];
    const float inv = 1.f / (g3 + EPSV);
    const float t   = lam2[k] * inv;
    const bool hasD = (m < MM-1), hasR = (n < NN-1);
    float vc[3], vd[3], vr[3];
    #pragma unroll
    for (int c = 0; c < 3; ++c) {
        const int idx = (b*CC + c)*MN + mn;
        vc[c] = 2.f*xaft[idx] - xbef[idx];
        vd[c] = hasD ? (2.f*xaft[idx+NN] - xbef[idx+NN]) : 0.f;
        vr[c] = hasR ? (2.f*xaft[idx+1]  - xbef[idx+1])  : 0.f;
    }
    const float cc0 = S3*(vc[0]+vc[1]+vc[2]);
    const float cc1 = S2*(vc[0]-vc[1]);
    const float cc2 = S6*(vc[0]+vc[1]) - 2.f*S6*vc[2];
    const float cd0 = S3*(vd[0]+vd[1]+vd[2]);
    const float cd1 = S2*(vd[0]-vd[1]);
    const float cd2 = S6*(vd[0]+vd[1]) - 2.f*S6*vd[2];
    const float cr0 = S3*(vr[0]+vr[1]+vr[2]);
    const float cr1 = S2*(vr[0]-vr[1]);
    const float cr2 = S6*(vr[0]+vr[1]) - 2.f*S6*vr[2];
    const float dv[3] = { hasD ? cd0-cc0 : 0.f, hasD ? cd1-cc1 : 0.f, hasD ? cd2-cc2 : 0.f };
    const float dh[3] = { hasR ? cr0-cc0 : 0.f, hasR ? cr1-cc1 : 0.f, hasR ? cr2-cc2 : 0.f };
    float yn[2][3], vv[2][3];
    #pragma unroll
    for (int e = 0; e < 3; ++e) {
        const int i0 = ((b*2 + 0)*CC + e)*MN + mn;
        const int i1 = ((b*2 + 1)*CC + e)*MN + mn;
        yn[0][e] = y1[i0] + g3*dv[e];
        yn[1][e] = y1[i1] + g3*dh[e];
        vv[0][e] = yn[0][e]*inv;
        vv[1][e] = yn[1][e]*inv;
    }
    const float nl = sqrtf(vv[0][0]*vv[0][0] + vv[1][0]*vv[1][0]);
    const float sl = fmaxf(0.f, 1.f - t / fmaxf(nl, 1e-12f));
    const float nc = sqrtf(vv[0][1]*vv[0][1] + vv[0][2]*vv[0][2]
                         + vv[1][1]*vv[1][1] + vv[1][2]*vv[1][2]);
    const float sc = fmaxf(0.f, 1.f - t*W_CH / fmaxf(nc, 1e-12f));
    #pragma unroll
    for (int e = 0; e < 3; ++e) {
        const float se = (e == 0) ? sl : sc;
        const int i0 = ((b*2 + 0)*CC + e)*MN + mn;
        const int i1 = ((b*2 + 1)*CC + e)*MN + mn;
        y1[i0] = yn[0][e] - g3*(vv[0][e]*se);
        y1[i1] = yn[1][e] - g3*(vv[1][e]*se);
    }
}

extern "C" void kernel_launch(void* const* d_in, const int* in_sizes, int n_in,
                              void* d_out, int out_size, void* d_ws, size_t ws_size,
                              hipStream_t stream) {
    const float* z    = (const float*)d_in[0];
    const float* mask = (const float*)d_in[1];
    const float* a0   = (const float*)d_in[2];
    const float* Bw   = (const float*)d_in[3];
    const float* lam1 = (const float*)d_in[4];
    const float* lam2 = (const float*)d_in[5];
    const float* gam1 = (const float*)d_in[6];
    const float* gam2 = (const float*)d_in[7];
    const float* gam3 = (const float*)d_in[8];
    float* out = (float*)d_out;

    float* ws = (float*)d_ws;
    float* xA   = ws; ws += IMG;
    float* xB   = ws; ws += IMG;
    float* y1   = ws; ws += 2*IMG;
    float* y2   = ws; ws += IMG;
    float* rb   = ws; ws += IMG;
    float* part = ws; ws += PSPLIT*IMG;
    float* sums = ws; ws += KITER*64;
    const size_t base_need = (size_t)((6 + PSPLIT)*IMG + KITER*64) * sizeof(float);
    float* a_ws;
    if (ws_size >= base_need + (size_t)ASZ * sizeof(float)) {
        a_ws = ws;                    // normal: a lives in workspace
    } else {
        a_ws = (float*)d_in[2];       // fallback: in-place on a0 (restored per launch)
    }

    hipMemsetAsync(y1, 0, sizeof(float)*2*IMG, stream);
    hipMemsetAsync(sums, 0, sizeof(float)*KITER*64, stream);
    // y2 needs no init: k==0 treats y2_bef as 0 and overwrites.

    dim3 gconv(NN/TD, MM/TD, MB*CC*PSPLIT);       // 3 x 3 x 96 = 864 blocks
    const int ew_blocks = (MB*MN) / 256;          // 576 (exact)

    const float* xbef = z;
    float* xaft = xA;
    const float* acur = a0;
    for (int k = 0; k < KITER; ++k) {
        k_conv_part<<<gconv, 256, 0, stream>>>(acur, Bw, part);
        float* xt = (k == KITER-1) ? out : xaft;
        k_x_update<<<ew_blocks, 256, 0, stream>>>(xbef, part, rb, y1, y2, mask, z,
                                                  gam1, gam3, k, xt, sums);
        if (k < KITER-1) {
            k_a_update<<<gconv, 256, 0, stream>>>(acur, rb, Bw, a_ws, gam2, lam1, k);
            k_y1_update<<<ew_blocks, 256, 0, stream>>>(y1, xt, xbef, gam3, lam2, k);
            acur = a_ws;
            xbef = xt;
            xaft = (xt == xA) ? xB : xA;
        }
    }
    (void)in_sizes; (void)n_in; (void)out_size;
}

// Round 5
// 729.140 us; speedup vs baseline: 1.3926x; 1.3926x over previous
//
#include <hip/hip_runtime.h>

#define MB 4
#define CC 3
#define MM 192
#define NN 192
#define PP 32
#define KITER 8
#define MN (MM*NN)          /* 36864  */
#define CMN (CC*MN)         /* 110592 */
#define IMG (MB*CMN)        /* 442368 */
#define ASZ (MB*PP*CMN)     /* 14155776 */

#define PSPLIT 8
#define PCHUNK (PP/PSPLIT)  /* 4 planes per conv block */

#define PSPLIT_A 4
#define PCHUNK_A (PP/PSPLIT_A) /* 8 planes per a_update block */

#define S3 0.57735026918962576f
#define S2 0.70710678118654752f
#define S6 0.40824829046386302f
#define W_CH 0.8f
#define EPSV 1e-8f
#define RADIUS 6.6510751010644885f   /* 0.02*sqrt(3*192*192) */

/* conv_part geometry: 64x64 tile, 4x4 outputs/thread */
#define TD 64
#define HALO 3
#define HT2 70
#define HS2 76       /* LDS row stride (16B-aligned, good bank spread) */
#define STG (HT2*HT2)   /* 4900 */
#define NSTG 20         /* ceil(4900/256) */

/* a_update geometry: 32x32 tile, 1x4 outputs/thread (memory-bound: favor occupancy) */
#define TDIM 32
#define HT 38
#define HS 40
#define HTT (HT*HT)  /* 1444 */

__device__ __forceinline__ float softf(float x, float t) {
    float m = fabsf(x) - t;
    return m > 0.f ? copysignf(m, x) : 0.f;
}

// partial conv: part[s] = sum_{p in chunk s} xcorr(a[b,p,c], B[p,c])
__global__ __launch_bounds__(256) void k_conv_part(
    const float* __restrict__ a, const float* __restrict__ Bw,
    float* __restrict__ part)
{
    const int bc = blockIdx.z % (MB*CC);
    const int s  = blockIdx.z / (MB*CC);
    const int b = bc / CC, c = bc % CC;
    const int m0 = blockIdx.y * TD, n0 = blockIdx.x * TD;
    __shared__ float sT[HT2 * HS2];
    const int tc = threadIdx.x & 15;   // cols tc*4..+3
    const int tr = threadIdx.x >> 4;   // rows tr*4..+3
    const int p0 = s * PCHUNK;
    const int sr0 = threadIdx.x / HT2;
    const int sc0 = threadIdx.x - sr0*HT2;

    float pf[NSTG];
    {   // prefetch plane p0 (incremental index walk: i += 256 -> sr+=3, sc+=46)
        const float* ap = a + (size_t)((b*PP + p0)*CC + c) * MN;
        int sr = sr0, sc = sc0;
        #pragma unroll
        for (int j = 0; j < NSTG; ++j) {
            const int gm = m0 + sr - HALO, gn = n0 + sc - HALO;
            const bool ok = (sr < HT2) && ((unsigned)gm < MM) && ((unsigned)gn < NN);
            pf[j] = ok ? ap[gm*NN + gn] : 0.f;
            sc += 46; sr += 3; if (sc >= HT2) { sc -= HT2; sr += 1; }
        }
    }
    float acc[4][4];
    #pragma unroll
    for (int r = 0; r < 4; ++r)
        #pragma unroll
        for (int j = 0; j < 4; ++j) acc[r][j] = 0.f;

    #pragma unroll 1
    for (int pp = 0; pp < PCHUNK; ++pp) {
        __syncthreads();   // prior compute done, safe to overwrite LDS
        {   // stage pf -> LDS
            int sr = sr0, sc = sc0, lofs = sr0*HS2 + sc0;
            #pragma unroll
            for (int j = 0; j < NSTG; ++j) {
                if (sr < HT2) sT[lofs] = pf[j];
                sc += 46; lofs += 3*HS2 + 46; sr += 3;
                if (sc >= HT2) { sc -= HT2; sr += 1; lofs += HS2 - HT2; }
            }
        }
        __syncthreads();
        if (pp + 1 < PCHUNK) {   // issue next plane's loads; hide under compute
            const float* ap = a + (size_t)((b*PP + p0 + pp + 1)*CC + c) * MN;
            int sr = sr0, sc = sc0;
            #pragma unroll
            for (int j = 0; j < NSTG; ++j) {
                const int gm = m0 + sr - HALO, gn = n0 + sc - HALO;
                const bool ok = (sr < HT2) && ((unsigned)gm < MM) && ((unsigned)gn < NN);
                pf[j] = ok ? ap[gm*NN + gn] : 0.f;
                sc += 46; sr += 3; if (sc >= HT2) { sc -= HT2; sr += 1; }
            }
        }
        const float* bp = Bw + ((p0 + pp)*CC + c) * 49;
        #pragma unroll
        for (int ir = 0; ir < 10; ++ir) {
            const int base = (tr*4 + ir)*HS2 + tc*4;
            const float4 q0 = *(const float4*)&sT[base];
            const float4 q1 = *(const float4*)&sT[base + 4];
            const float2 q2 = *(const float2*)&sT[base + 8];
            const float w[10] = {q0.x,q0.y,q0.z,q0.w,q1.x,q1.y,q1.z,q1.w,q2.x,q2.y};
            #pragma unroll
            for (int r = 0; r < 4; ++r) {
                const int du = ir - r;
                if (du >= 0 && du <= 6) {
                    #pragma unroll
                    for (int v = 0; v < 7; ++v) {
                        const float bv = bp[du*7 + v];
                        #pragma unroll
                        for (int j = 0; j < 4; ++j) acc[r][j] += w[v+j] * bv;
                    }
                }
            }
        }
    }
    #pragma unroll
    for (int r = 0; r < 4; ++r) {
        const int idx = (b*CC + c)*MN + (m0 + tr*4 + r)*NN + n0 + tc*4;
        float4 o; o.x = acc[r][0]; o.y = acc[r][1]; o.z = acc[r][2]; o.w = acc[r][3];
        *(float4*)&part[(size_t)s*IMG + idx] = o;
    }
}

// a_out = soft(a_in + g2 * convT_csc(r, B), g2*lam1)  for p in chunk s
// 32x32 tile, 1x4 out/thread: memory-bound kernel, keep VGPR low / occupancy high.
__global__ __launch_bounds__(256) void k_a_update(
    const float* __restrict__ a_in, const float* __restrict__ rr,
    const float* __restrict__ Bw, float* __restrict__ a_out,
    const float* __restrict__ gam2, const float* __restrict__ lam1, int k)
{
    const int bc = blockIdx.z % (MB*CC);
    const int s  = blockIdx.z / (MB*CC);
    const int b = bc / CC, c = bc % CC;
    const int m0 = blockIdx.y * TDIM, n0 = blockIdx.x * TDIM;
    const float g2  = gam2[k];
    const float thr = g2 * lam1[k];
    __shared__ float sT[HT * HS];
    const float* rp = rr + (b*CC + c)*MN;
    for (int i = threadIdx.x; i < HTT; i += 256) {
        const int im = i / HT, in = i - im*HT;
        const int gm = m0 + im - 3, gn = n0 + in - 3;
        float v = 0.f;
        if ((unsigned)gm < MM && (unsigned)gn < NN) v = rp[gm*NN + gn];
        sT[im*HS + in] = v;
    }
    __syncthreads();
    const int row = threadIdx.x >> 3;
    const int tg  = threadIdx.x & 7;
    const int gm = m0 + row;
    const int gn = n0 + tg*4;
    const int p0 = s * PCHUNK_A;
    #pragma unroll 1
    for (int pp = 0; pp < PCHUNK_A; ++pp) {
        const int p = p0 + pp;
        const float* bp = Bw + (p*CC + c) * 49;
        float acc[4] = {0.f, 0.f, 0.f, 0.f};
        #pragma unroll
        for (int u = 0; u < 7; ++u) {
            const int base = (row + 6 - u)*HS + tg*4;
            const float4 q0 = *(const float4*)&sT[base];
            const float4 q1 = *(const float4*)&sT[base + 4];
            const float2 q2 = *(const float2*)&sT[base + 8];
            const float rv[10] = {q0.x,q0.y,q0.z,q0.w,q1.x,q1.y,q1.z,q1.w,q2.x,q2.y};
            #pragma unroll
            for (int v = 0; v < 7; ++v) {
                const float bv = bp[u*7 + v];
                acc[0] += rv[6-v] * bv;
                acc[1] += rv[7-v] * bv;
                acc[2] += rv[8-v] * bv;
                acc[3] += rv[9-v] * bv;
            }
        }
        const size_t idx = (size_t)((b*PP + p)*CC + c)*MN + gm*NN + gn;
        const float4 av = *(const float4*)&a_in[idx];
        float4 o;
        o.x = softf(av.x + g2*acc[0], thr);
        o.y = softf(av.y + g2*acc[1], thr);
        o.z = softf(av.z + g2*acc[2], thr);
        o.w = softf(av.w + g2*acc[3], thr);
        *(float4*)&a_out[idx] = o;
    }
}

// Fused: lazy y2 projection (iter k-1) + fold conv partials + x update +
//        y2 accumulation + per-batch norm reduction (one atomic/block).
// sums layout: sums[k*64 + b*16]
__global__ __launch_bounds__(256) void k_x_update(
    const float* __restrict__ xbef, const float* __restrict__ part,
    float* __restrict__ rb,
    const float* __restrict__ y1, float* __restrict__ y2,
    const float* __restrict__ mask, const float* __restrict__ z,
    const float* __restrict__ gam1, const float* __restrict__ gam3, int k,
    float* __restrict__ xaft, float* __restrict__ sums)
{
    const int i = blockIdx.x*256 + threadIdx.x;   // grid exactly covers MB*MN
    const int b = i / MN, mn = i - b*MN;
    const int m = mn / NN, n = mn - m*NN;
    const float g1 = gam1[k];
    const float g3 = gam3[k];
    const float inv3 = 1.f / (g3 + EPSV);
    float g3p = 0.f, invp = 0.f, scale_prev = 0.f;
    if (k > 0) {
        g3p  = gam3[k-1];
        invp = 1.f / (g3p + EPSV);
        const float nrm = sqrtf(sums[(k-1)*64 + b*16]);
        scale_prev = fminf(1.f, RADIUS / fmaxf(nrm, 1e-12f));
    }
    float dt[3];
    #pragma unroll
    for (int e = 0; e < 3; ++e) {
        const float* yv = y1 + ((size_t)(b*2 + 0)*CC + e)*MN;
        const float* yh = y1 + ((size_t)(b*2 + 1)*CC + e)*MN;
        float dv = (m > 0 ? yv[mn - NN] : 0.f) - (m < MM-1 ? yv[mn] : 0.f);
        float dh = (n > 0 ? yh[mn - 1]  : 0.f) - (n < NN-1 ? yh[mn] : 0.f);
        dt[e] = dv + dh;
    }
    const float ct0 = S3*dt[0] + S2*dt[1] + S6*dt[2];
    const float ct1 = S3*dt[0] - S2*dt[1] + S6*dt[2];
    const float ct2 = S3*dt[0]            - 2.f*S6*dt[2];
    const float ct[3] = {ct0, ct1, ct2};
    const bool last = (k == KITER-1);
    float dsq = 0.f;
    #pragma unroll
    for (int c = 0; c < 3; ++c) {
        const int idx = (b*CC + c)*MN + mn;
        float conv = 0.f;
        #pragma unroll
        for (int ss = 0; ss < PSPLIT; ++ss) conv += part[(size_t)ss*IMG + idx];
        const float xb = xbef[idx];
        const float r = xb - conv;
        const float zi = z[idx];
        const float mk = mask[idx];
        float y2b = 0.f;
        if (k > 0) {   // lazily apply iter-(k-1) L2-ball projection
            const float yr = y2[idx];
            const float d = yr*invp - zi;
            y2b = yr - g3p*(zi + d*scale_prev);
        }
        float x = xb - g1*(r + ct[c] + mk*y2b);
        x = fminf(fmaxf(x, 0.f), 1.f);
        xaft[idx] = x;
        if (!last) {
            rb[idx] = r;
            const float v  = 2.f*x - xb;
            const float yn = y2b + g3*(mk*v);
            y2[idx] = yn;               // post-acc, pre-proj (proj applied lazily)
            const float d2 = yn*inv3 - zi;
            dsq += d2*d2;
        }
    }
    if (!last) {
        #pragma unroll
        for (int off = 32; off > 0; off >>= 1) dsq += __shfl_down(dsq, off, 64);
        __shared__ float red[4];
        if ((threadIdx.x & 63) == 0) red[threadIdx.x >> 6] = dsq;
        __syncthreads();
        if (threadIdx.x == 0)
            atomicAdd(&sums[k*64 + b*16], red[0] + red[1] + red[2] + red[3]);
    }
}

// y1 += g3*Dop(Cop(v)); y1 -= g3*prox_dvtv(y1/(g3+eps), lam2/(g3+eps), w)
__global__ __launch_bounds__(256) void k_y1_update(
    float* __restrict__ y1, const float* __restrict__ xaft,
    const float* __restrict__ xbef,
    const float* __restrict__ gam3, const float* __restrict__ lam2, int k)
{
    const int i = blockIdx.x*256 + threadIdx.x;
    if (i >= MB*MN) return;
    const int b = i / MN, mn = i - b*MN;
    const int m = mn / NN, n = mn - m*NN;
    const float g3  = gam3[k];
    const float inv = 1.f / (g3 + EPSV);
    const float t   = lam2[k] * inv;
    const bool hasD = (m < MM-1), hasR = (n < NN-1);
    float vc[3], vd[3], vr[3];
    #pragma unroll
    for (int c = 0; c < 3; ++c) {
        const int idx = (b*CC + c)*MN + mn;
        vc[c] = 2.f*xaft[idx] - xbef[idx];
        vd[c] = hasD ? (2.f*xaft[idx+NN] - xbef[idx+NN]) : 0.f;
        vr[c] = hasR ? (2.f*xaft[idx+1]  - xbef[idx+1])  : 0.f;
    }
    const float cc0 = S3*(vc[0]+vc[1]+vc[2]);
    const float cc1 = S2*(vc[0]-vc[1]);
    const float cc2 = S6*(vc[0]+vc[1]) - 2.f*S6*vc[2];
    const float cd0 = S3*(vd[0]+vd[1]+vd[2]);
    const float cd1 = S2*(vd[0]-vd[1]);
    const float cd2 = S6*(vd[0]+vd[1]) - 2.f*S6*vd[2];
    const float cr0 = S3*(vr[0]+vr[1]+vr[2]);
    const float cr1 = S2*(vr[0]-vr[1]);
    const float cr2 = S6*(vr[0]+vr[1]) - 2.f*S6*vr[2];
    const float dv[3] = { hasD ? cd0-cc0 : 0.f, hasD ? cd1-cc1 : 0.f, hasD ? cd2-cc2 : 0.f };
    const float dh[3] = { hasR ? cr0-cc0 : 0.f, hasR ? cr1-cc1 : 0.f, hasR ? cr2-cc2 : 0.f };
    float yn[2][3], vv[2][3];
    #pragma unroll
    for (int e = 0; e < 3; ++e) {
        const int i0 = ((b*2 + 0)*CC + e)*MN + mn;
        const int i1 = ((b*2 + 1)*CC + e)*MN + mn;
        yn[0][e] = y1[i0] + g3*dv[e];
        yn[1][e] = y1[i1] + g3*dh[e];
        vv[0][e] = yn[0][e]*inv;
        vv[1][e] = yn[1][e]*inv;
    }
    const float nl = sqrtf(vv[0][0]*vv[0][0] + vv[1][0]*vv[1][0]);
    const float sl = fmaxf(0.f, 1.f - t / fmaxf(nl, 1e-12f));
    const float nc = sqrtf(vv[0][1]*vv[0][1] + vv[0][2]*vv[0][2]
                         + vv[1][1]*vv[1][1] + vv[1][2]*vv[1][2]);
    const float sc = fmaxf(0.f, 1.f - t*W_CH / fmaxf(nc, 1e-12f));
    #pragma unroll
    for (int e = 0; e < 3; ++e) {
        const float se = (e == 0) ? sl : sc;
        const int i0 = ((b*2 + 0)*CC + e)*MN + mn;
        const int i1 = ((b*2 + 1)*CC + e)*MN + mn;
        y1[i0] = yn[0][e] - g3*(vv[0][e]*se);
        y1[i1] = yn[1][e] - g3*(vv[1][e]*se);
    }
}

extern "C" void kernel_launch(void* const* d_in, const int* in_sizes, int n_in,
                              void* d_out, int out_size, void* d_ws, size_t ws_size,
                              hipStream_t stream) {
    const float* z    = (const float*)d_in[0];
    const float* mask = (const float*)d_in[1];
    const float* a0   = (const float*)d_in[2];
    const float* Bw   = (const float*)d_in[3];
    const float* lam1 = (const float*)d_in[4];
    const float* lam2 = (const float*)d_in[5];
    const float* gam1 = (const float*)d_in[6];
    const float* gam2 = (const float*)d_in[7];
    const float* gam3 = (const float*)d_in[8];
    float* out = (float*)d_out;

    float* ws = (float*)d_ws;
    float* xA   = ws; ws += IMG;
    float* xB   = ws; ws += IMG;
    float* y1   = ws; ws += 2*IMG;
    float* y2   = ws; ws += IMG;
    float* rb   = ws; ws += IMG;
    float* part = ws; ws += PSPLIT*IMG;
    float* sums = ws; ws += KITER*64;
    const size_t base_need = (size_t)((6 + PSPLIT)*IMG + KITER*64) * sizeof(float);
    float* a_ws;
    if (ws_size >= base_need + (size_t)ASZ * sizeof(float)) {
        a_ws = ws;                    // normal: a lives in workspace
    } else {
        a_ws = (float*)d_in[2];       // fallback: in-place on a0 (restored per launch)
    }

    hipMemsetAsync(y1, 0, sizeof(float)*2*IMG, stream);
    hipMemsetAsync(sums, 0, sizeof(float)*KITER*64, stream);
    // y2 needs no init: k==0 treats y2_bef as 0 and overwrites.

    dim3 gconv(NN/TD, MM/TD, MB*CC*PSPLIT);       // 3 x 3 x 96 = 864 blocks
    dim3 ga(NN/TDIM, MM/TDIM, MB*CC*PSPLIT_A);    // 6 x 6 x 48 = 1728 blocks
    const int ew_blocks = (MB*MN) / 256;          // 576 (exact)

    const float* xbef = z;
    float* xaft = xA;
    const float* acur = a0;
    for (int k = 0; k < KITER; ++k) {
        k_conv_part<<<gconv, 256, 0, stream>>>(acur, Bw, part);
        float* xt = (k == KITER-1) ? out : xaft;
        k_x_update<<<ew_blocks, 256, 0, stream>>>(xbef, part, rb, y1, y2, mask, z,
                                                  gam1, gam3, k, xt, sums);
        if (k < KITER-1) {
            k_a_update<<<ga, 256, 0, stream>>>(acur, rb, Bw, a_ws, gam2, lam1, k);
            k_y1_update<<<ew_blocks, 256, 0, stream>>>(y1, xt, xbef, gam3, lam2, k);
            acur = a_ws;
            xbef = xt;
            xaft = (xt == xA) ? xB : xA;
        }
    }
    (void)in_sizes; (void)n_in; (void)out_size;
}